// Round 4
// baseline (127.518 us; speedup 1.0000x reference)
//
#include <hip/hip_runtime.h>

#define BATCH 8192
#define HIDDEN 8192
#define NUM_SEEDS 16
#define CHUNK 512                 // HIDDEN / NUM_SEEDS
#define H4 (HIDDEN / 4)           // 2048 float4s per row
#define N4 ((long long)BATCH * HIDDEN / 4)   // 16,777,216 float4s total

#define GRID 2048
#define BLOCK 256
#define NTHREADS ((long long)GRID * BLOCK)   // 524,288 (multiple of H4!)
#define ITERS (N4 / NTHREADS)                // 32, exact — no tail

typedef float f32x4 __attribute__((ext_vector_type(4)));

__global__ __launch_bounds__(BLOCK) void seed_layer_kernel(
    const f32x4* __restrict__ x4,
    const int*   __restrict__ lifecycle,
    const int*   __restrict__ blueprint,
    const int*   __restrict__ strategy,
    const f32x4* __restrict__ weights4,
    f32x4*       __restrict__ out4)
{
    const int tid = blockIdx.x * BLOCK + threadIdx.x;   // 0 .. 524287

    // NTHREADS is a multiple of H4, so the feature position (and thus the
    // seed id, coeffs, and weight element) is loop-invariant per thread.
    const int h4  = tid & (H4 - 1);          // float4 index within a row
    const int sid = h4 >> 7;                 // (h4*4) / CHUNK

    const int life = lifecycle[sid];         // wave-nearly-uniform, L1-hot
    const int strt = strategy[sid];
    const int bp   = blueprint[sid];
    const bool active = (life >= 3) && (life <= 6);

    // out = cx*x + cw*w + cm*(x*w)  ==  (cx + cm*w)*x + cw*w  ==  a*x + b
    float cx, cw, cm;
    if (!active)         { cx = 1.0f; cw = 0.0f; cm = 0.0f; }   // identity
    else if (strt == 0)  { cx = 0.0f; cw = 0.0f; cm = 1.0f; }   // x*w
    else if (strt == 1)  { cx = 1.0f; cw = 1.0f; cm = 0.0f; }   // x+w
    else                 { cx = 0.5f; cw = 0.5f; cm = 0.0f; }   // 0.5x+0.5w

    const f32x4 wv = weights4[bp * H4 + h4];             // one gather, cached
    f32x4 a, b;
    a.x = fmaf(cm, wv.x, cx); a.y = fmaf(cm, wv.y, cx);
    a.z = fmaf(cm, wv.z, cx); a.w = fmaf(cm, wv.w, cx);
    b.x = cw * wv.x; b.y = cw * wv.y; b.z = cw * wv.z; b.w = cw * wv.w;

    const f32x4* px = x4   + tid;
    f32x4*       po = out4 + tid;

#pragma unroll 4
    for (int it = 0; it < ITERS; ++it) {
        const long long off = (long long)it * NTHREADS;
        const f32x4 xv = px[off];           // normal cached path (L2-coalesced)
        f32x4 o;
        o.x = fmaf(a.x, xv.x, b.x);
        o.y = fmaf(a.y, xv.y, b.y);
        o.z = fmaf(a.z, xv.z, b.z);
        o.w = fmaf(a.w, xv.w, b.w);
        po[off] = o;
    }
}

extern "C" void kernel_launch(void* const* d_in, const int* in_sizes, int n_in,
                              void* d_out, int out_size, void* d_ws, size_t ws_size,
                              hipStream_t stream) {
    const f32x4* x4        = (const f32x4*)d_in[0];
    const int*   lifecycle = (const int*)d_in[1];
    const int*   blueprint = (const int*)d_in[2];
    const int*   strategy  = (const int*)d_in[3];
    const f32x4* weights4  = (const f32x4*)d_in[4];
    // d_in[5] is chunk_size scalar (512) — compile-time constant here.

    f32x4* out4 = (f32x4*)d_out;

    seed_layer_kernel<<<GRID, BLOCK, 0, stream>>>(
        x4, lifecycle, blueprint, strategy, weights4, out4);
}

// Round 5
// 106.884 us; speedup vs baseline: 1.1930x; 1.1930x over previous
//
#include <hip/hip_runtime.h>

#define BATCH 8192
#define HIDDEN 8192
#define NUM_SEEDS 16
#define CHUNK 512                 // HIDDEN / NUM_SEEDS
#define H4 (HIDDEN / 4)           // 2048 float4s per row
#define N4 ((long long)BATCH * HIDDEN / 4)   // 16,777,216 float4s total

#define GRID 2048
#define BLOCK 256

typedef float f32x4 __attribute__((ext_vector_type(4)));

__global__ __launch_bounds__(BLOCK) void seed_layer_kernel(
    const f32x4* __restrict__ x4,
    const int*   __restrict__ lifecycle,
    const int*   __restrict__ blueprint,
    const int*   __restrict__ strategy,
    const f32x4* __restrict__ weights4,
    f32x4*       __restrict__ out4,
    long long half)                      // N4/2, runtime arg -> dynamic loop
{
    const int tid = blockIdx.x * BLOCK + threadIdx.x;   // 0 .. 524287

    // Grid-stride step (= GRID*BLOCK = 524288) and `half` (= 8388608) are
    // both multiples of H4, so h4/sid/coeffs/w are loop-invariant AND shared
    // by both streams.
    const int h4  = tid & (H4 - 1);          // float4 index within a row
    const int sid = h4 >> 7;                 // (h4*4) / CHUNK

    const int life = lifecycle[sid];
    const int strt = strategy[sid];
    const int bp   = blueprint[sid];
    const bool active = (life >= 3) && (life <= 6);

    // out = cx*x + cw*w + cm*(x*w)  ==  (cx + cm*w)*x + cw*w  ==  a*x + b
    float cx, cw, cm;
    if (!active)         { cx = 1.0f; cw = 0.0f; cm = 0.0f; }   // identity
    else if (strt == 0)  { cx = 0.0f; cw = 0.0f; cm = 1.0f; }   // x*w
    else if (strt == 1)  { cx = 1.0f; cw = 1.0f; cm = 0.0f; }   // x+w
    else                 { cx = 0.5f; cw = 0.5f; cm = 0.0f; }   // 0.5x+0.5w

    const f32x4 wv = weights4[bp * H4 + h4];             // one gather, cached
    f32x4 a, b;
    a.x = fmaf(cm, wv.x, cx); a.y = fmaf(cm, wv.y, cx);
    a.z = fmaf(cm, wv.z, cx); a.w = fmaf(cm, wv.w, cx);
    b.x = cw * wv.x; b.y = cw * wv.y; b.z = cw * wv.z; b.w = cw * wv.w;

    const long long stride = (long long)GRID * BLOCK;

    // Dynamic-bound loop (compiler keeps the natural per-iteration schedule,
    // which outperformed static unrolling: R1=108.6us vs R4=127.5us).
    // Two independent far-apart streams per iteration double the MLP.
    for (long long i = tid; i < half; i += stride) {
        const f32x4 xv0 = x4[i];
        const f32x4 xv1 = x4[i + half];
        f32x4 o0, o1;
        o0.x = fmaf(a.x, xv0.x, b.x);
        o0.y = fmaf(a.y, xv0.y, b.y);
        o0.z = fmaf(a.z, xv0.z, b.z);
        o0.w = fmaf(a.w, xv0.w, b.w);
        o1.x = fmaf(a.x, xv1.x, b.x);
        o1.y = fmaf(a.y, xv1.y, b.y);
        o1.z = fmaf(a.z, xv1.z, b.z);
        o1.w = fmaf(a.w, xv1.w, b.w);
        out4[i] = o0;
        out4[i + half] = o1;
    }
}

extern "C" void kernel_launch(void* const* d_in, const int* in_sizes, int n_in,
                              void* d_out, int out_size, void* d_ws, size_t ws_size,
                              hipStream_t stream) {
    const f32x4* x4        = (const f32x4*)d_in[0];
    const int*   lifecycle = (const int*)d_in[1];
    const int*   blueprint = (const int*)d_in[2];
    const int*   strategy  = (const int*)d_in[3];
    const f32x4* weights4  = (const f32x4*)d_in[4];
    // d_in[5] is chunk_size scalar (512) — compile-time constant here.

    f32x4* out4 = (f32x4*)d_out;
    const long long half = N4 / 2;   // 8,388,608

    seed_layer_kernel<<<GRID, BLOCK, 0, stream>>>(
        x4, lifecycle, blueprint, strategy, weights4, out4, half);
}

// Round 6
// 85.357 us; speedup vs baseline: 1.4939x; 1.2522x over previous
//
#include <hip/hip_runtime.h>

#define BATCH 8192
#define HIDDEN 8192
#define NUM_SEEDS 16
#define CHUNK 512                 // HIDDEN / NUM_SEEDS
#define H4 (HIDDEN / 4)           // 2048 float4s per row
#define N4 ((long long)BATCH * HIDDEN / 4)   // 16,777,216 float4s total

#define GRID 2048
#define BLOCK 256

typedef float f32x4 __attribute__((ext_vector_type(4)));

__global__ __launch_bounds__(BLOCK) void seed_layer_kernel(
    const f32x4* __restrict__ x4,
    const int*   __restrict__ lifecycle,
    const int*   __restrict__ blueprint,
    const int*   __restrict__ strategy,
    const f32x4* __restrict__ weights4,
    f32x4*       __restrict__ out4,
    long long half)                      // N4/2, runtime arg -> dynamic loop
{
    const int tid = blockIdx.x * BLOCK + threadIdx.x;   // 0 .. 524287

    // Grid-stride step (= GRID*BLOCK = 524288) and `half` (= 8388608) are
    // both multiples of H4, so h4/sid/coeffs/w are loop-invariant AND shared
    // by both streams.
    const int h4  = tid & (H4 - 1);          // float4 index within a row
    const int sid = h4 >> 7;                 // (h4*4) / CHUNK

    const int life = lifecycle[sid];
    const int strt = strategy[sid];
    const int bp   = blueprint[sid];
    const bool active = (life >= 3) && (life <= 6);

    // out = cx*x + cw*w + cm*(x*w)  ==  (cx + cm*w)*x + cw*w  ==  a*x + b
    float cx, cw, cm;
    if (!active)         { cx = 1.0f; cw = 0.0f; cm = 0.0f; }   // identity
    else if (strt == 0)  { cx = 0.0f; cw = 0.0f; cm = 1.0f; }   // x*w
    else if (strt == 1)  { cx = 1.0f; cw = 1.0f; cm = 0.0f; }   // x+w
    else                 { cx = 0.5f; cw = 0.5f; cm = 0.0f; }   // 0.5x+0.5w

    const f32x4 wv = weights4[bp * H4 + h4];             // one gather, cached
    f32x4 a, b;
    a.x = fmaf(cm, wv.x, cx); a.y = fmaf(cm, wv.y, cx);
    a.z = fmaf(cm, wv.z, cx); a.w = fmaf(cm, wv.w, cx);
    b.x = cw * wv.x; b.y = cw * wv.y; b.z = cw * wv.z; b.w = cw * wv.w;

    const long long stride = (long long)GRID * BLOCK;

    // Dynamic-bound loop (R5-proven shape: 106.9us vs 127.5us static unroll).
    // Cached LOADS (so x stays Infinity-Cache-resident) + NON-TEMPORAL STORES
    // (so the out stream doesn't evict x from L3). A/B vs R5 isolates NT-store.
    for (long long i = tid; i < half; i += stride) {
        const f32x4 xv0 = x4[i];
        const f32x4 xv1 = x4[i + half];
        f32x4 o0, o1;
        o0.x = fmaf(a.x, xv0.x, b.x);
        o0.y = fmaf(a.y, xv0.y, b.y);
        o0.z = fmaf(a.z, xv0.z, b.z);
        o0.w = fmaf(a.w, xv0.w, b.w);
        o1.x = fmaf(a.x, xv1.x, b.x);
        o1.y = fmaf(a.y, xv1.y, b.y);
        o1.z = fmaf(a.z, xv1.z, b.z);
        o1.w = fmaf(a.w, xv1.w, b.w);
        __builtin_nontemporal_store(o0, out4 + i);
        __builtin_nontemporal_store(o1, out4 + i + half);
    }
}

extern "C" void kernel_launch(void* const* d_in, const int* in_sizes, int n_in,
                              void* d_out, int out_size, void* d_ws, size_t ws_size,
                              hipStream_t stream) {
    const f32x4* x4        = (const f32x4*)d_in[0];
    const int*   lifecycle = (const int*)d_in[1];
    const int*   blueprint = (const int*)d_in[2];
    const int*   strategy  = (const int*)d_in[3];
    const f32x4* weights4  = (const f32x4*)d_in[4];
    // d_in[5] is chunk_size scalar (512) — compile-time constant here.

    f32x4* out4 = (f32x4*)d_out;
    const long long half = N4 / 2;   // 8,388,608

    seed_layer_kernel<<<GRID, BLOCK, 0, stream>>>(
        x4, lifecycle, blueprint, strategy, weights4, out4, half);
}